// Round 5
// baseline (163.080 us; speedup 1.0000x reference)
//
#include <hip/hip_runtime.h>
#include <stdint.h>

#define B_   8
#define KB_  16
#define SEQ_ 512
#define HID_ 768

#define NKB  (HID_ / 32)         // 24 k-blocks (32 halves each) per row
#define QRB  (B_  * SEQ_ / 16)   // 256 Q row-blocks of 16 rows
#define KRB  (KB_ * SEQ_ / 16)   // 512 K row-blocks

typedef __attribute__((ext_vector_type(4))) _Float16 half4;
typedef __attribute__((ext_vector_type(8))) _Float16 half8;
typedef __attribute__((ext_vector_type(4))) float    floatx4;

#define GLOBAL_AS __attribute__((address_space(1)))
#define LDS_AS    __attribute__((address_space(3)))

// async 16B/lane global->LDS copy: LDS dest = base + lane*16 (wave-uniform base)
static __device__ __forceinline__ void async_tile16(const _Float16* g, _Float16* l)
{
    __builtin_amdgcn_global_load_lds((const GLOBAL_AS uint32_t*)g,
                                     (LDS_AS uint32_t*)l, 16, 0, 0);
}

// ---------------- prepass: L2-normalize rows -> fp16 in MFMA-fragment-tiled layout ----
// Tile = 16 rows x 32 k = 1KB, lane-major: element(row,k) at lane = row | ((k>>3)<<4),
// idx = k&7. One 256-thread block per 16-row block.
#define LP 776   // LDS row stride in halves

__global__ __launch_bounds__(256)
void prep_tile(const float* __restrict__ Q, const float* __restrict__ K,
               _Float16* __restrict__ Qt, _Float16* __restrict__ Kt)
{
    const int rb = blockIdx.x;   // 0..767
    const float* src;
    _Float16*    dst;
    if (rb < QRB) { src = Q + (size_t)rb * 16 * HID_;          dst = Qt + (size_t)rb * NKB * 512; }
    else          { src = K + (size_t)(rb - QRB) * 16 * HID_;  dst = Kt + (size_t)(rb - QRB) * NKB * 512; }

    __shared__ _Float16 Ls[16 * LP];
    const int wave = threadIdx.x >> 6;
    const int lane = threadIdx.x & 63;

#pragma unroll
    for (int rr = 0; rr < 4; ++rr) {
        int row = wave * 4 + rr;
        const float* s = src + (size_t)row * HID_;
        float4 v[3];
        float ss = 0.f;
#pragma unroll
        for (int it = 0; it < 3; ++it) {
            v[it] = *(const float4*)(s + lane * 4 + it * 256);
            ss += v[it].x * v[it].x + v[it].y * v[it].y + v[it].z * v[it].z + v[it].w * v[it].w;
        }
#pragma unroll
        for (int m = 1; m < 64; m <<= 1) ss += __shfl_xor(ss, m, 64);
        float sc = 1.0f / fmaxf(sqrtf(ss), 1e-12f);
#pragma unroll
        for (int it = 0; it < 3; ++it) {
            half4 h = { (_Float16)(v[it].x * sc), (_Float16)(v[it].y * sc),
                        (_Float16)(v[it].z * sc), (_Float16)(v[it].w * sc) };
            *(half4*)(Ls + row * LP + lane * 4 + it * 256) = h;
        }
    }
    __syncthreads();

#pragma unroll
    for (int rep = 0; rep < 6; ++rep) {
        int slot = rep * 256 + threadIdx.x;      // 0..1535 = 24 tiles x 64 lanes
        int kb   = slot >> 6;
        int ln   = slot & 63;
        int row  = ln & 15;
        int ko   = kb * 32 + (ln >> 4) * 8;
        half8 h = *(const half8*)(Ls + row * LP + ko);
        *(half8*)(dst + (size_t)kb * 512 + (size_t)ln * 8) = h;
    }
}

// ---------------- fused main: 128 s-rows x ALL 512 t-cols per block -------------------
// 512 threads = 8 waves in 2 (row) x 4 (col); wave tile 64x128 (af[4] x bf[8]).
// Complete sum-softmax per row in-block -> one atomicAdd per (i,j).
__global__ __launch_bounds__(512, 2)
void li_main(const _Float16* __restrict__ Qt, const _Float16* __restrict__ Kt,
             const float* __restrict__ alpha_p, const int* __restrict__ kmask,
             const int* __restrict__ qmask, float* __restrict__ out)
{
    const int st = blockIdx.x;   // s tile (0..3), 128 rows
    const int j  = blockIdx.y;
    const int i  = blockIdx.z;

    const int tid  = threadIdx.x;
    const int lane = tid & 63;
    const int wave = tid >> 6;        // 0..7
    const int quad = lane >> 4;
    const int l16  = lane & 15;
    const int wr   = wave >> 2;       // row half (0/1): rows wr*64..+63
    const int wc   = wave & 3;        // col quarter (0..3): cols wc*128..+127

    // double-buffered staging: 40 tiles (8 Q + 32 K) x 512 halves per buffer = 40 KB
    __shared__ _Float16 Sbuf[2][40 * 512];
    __shared__ float lred[4][128], nred[4][128];
    __shared__ float sred[2];

    const float araw  = *alpha_p;
    const float alpha = araw >= 0.f ? araw : 0.01f * araw;   // leaky_relu

    const int qbase = i * 32 + st * 8;   // first Q row-block
    const int kbase = j * 32;            // first K row-block (all of j)

    // staging assignment: wave stages tiles wave*5 .. wave*5+4
    const _Float16* gsrc[5];
    _Float16*       ldst0[5];
#pragma unroll
    for (int q = 0; q < 5; ++q) {
        int t   = wave * 5 + q;
        int rbg = (t < 8) ? (qbase + t) : (kbase + (t - 8));
        const _Float16* base = (t < 8) ? Qt : Kt;
        gsrc[q]  = base + (size_t)rbg * NKB * 512 + (size_t)lane * 8;
        ldst0[q] = &Sbuf[0][t * 512];
    }

    floatx4 acc[4][8];
#pragma unroll
    for (int rt = 0; rt < 4; ++rt)
#pragma unroll
        for (int ct = 0; ct < 8; ++ct)
            acc[rt][ct] = (floatx4){0.f, 0.f, 0.f, 0.f};

    // stage kb=0 into buffer 0
#pragma unroll
    for (int q = 0; q < 5; ++q)
        async_tile16(gsrc[q], ldst0[q]);

    for (int kb = 0; kb < NKB; ++kb) {
        const int b = kb & 1;
        __syncthreads();   // drains this-kb staging; fences prior reads of buf b^1
        if (kb + 1 < NKB) {
#pragma unroll
            for (int q = 0; q < 5; ++q)
                async_tile16(gsrc[q] + (size_t)(kb + 1) * 512, ldst0[q] + (b ^ 1) * 40 * 512);
        }
        const _Float16* Qs = &Sbuf[b][0];
        const _Float16* Ks = &Sbuf[b][8 * 512];
        half8 af[4], bf[8];
#pragma unroll
        for (int rt = 0; rt < 4; ++rt)
            af[rt] = *(const half8*)(Qs + (wr * 4 + rt) * 512 + lane * 8);
#pragma unroll
        for (int ct = 0; ct < 8; ++ct)
            bf[ct] = *(const half8*)(Ks + (wc * 8 + ct) * 512 + lane * 8);
#pragma unroll
        for (int rt = 0; rt < 4; ++rt)
#pragma unroll
            for (int ct = 0; ct < 8; ++ct)
                acc[rt][ct] = __builtin_amdgcn_mfma_f32_16x16x32_f16(af[rt], bf[ct], acc[rt][ct], 0, 0, 0);
    }

    // ---- epilogue: sum-softmax (logits in [-e,e] -> no max shift) over full t ----
    const int* km = kmask + j * SEQ_;
    int kmv[8]; float tgf[8];
#pragma unroll
    for (int ct = 0; ct < 8; ++ct) {
        int t_loc = wc * 128 + ct * 16 + l16;
        kmv[ct] = km[t_loc];
        tgf[ct] = (float)t_loc;
    }
#pragma unroll
    for (int rt = 0; rt < 4; ++rt) {
#pragma unroll
        for (int r = 0; r < 4; ++r) {
            float sgf = (float)(st * 128 + wr * 64 + rt * 16 + quad * 4 + r);
            float ps = 0.f, ns = 0.f;
#pragma unroll
            for (int ct = 0; ct < 8; ++ct) {
                float cv = acc[rt][ct][r];
                float e  = kmv[ct] ? __expf(cv * __expf(-alpha * fabsf(sgf - tgf[ct]))) : 0.f;
                ps += e;
                ns += e * cv;
            }
#pragma unroll
            for (int msk = 1; msk < 16; msk <<= 1) {
                ps += __shfl_xor(ps, msk, 64);
                ns += __shfl_xor(ns, msk, 64);
            }
            if (l16 == 0) {
                int rloc = wr * 64 + rt * 16 + quad * 4 + r;
                lred[wc][rloc] = ps;
                nred[wc][rloc] = ns;
            }
        }
    }
    __syncthreads();

    // merge 4 col-quarters -> final per-row score; block-sum 128 rows -> one atomic
    float sum = 0.f;
    if (tid < 128) {
        float l = lred[0][tid] + lred[1][tid] + lred[2][tid] + lred[3][tid];
        float n = nred[0][tid] + nred[1][tid] + nred[2][tid] + nred[3][tid];
        float sc = (l > 0.f) ? n / l : 0.f;
        if (qmask[i * SEQ_ + st * 128 + tid] == 0) sc = 0.f;
        sum = sc;
    }
    if (tid < 128) {
#pragma unroll
        for (int m = 1; m < 64; m <<= 1) sum += __shfl_xor(sum, m, 64);
        if (lane == 0) sred[wave] = sum;
    }
    __syncthreads();
    if (tid == 0) atomicAdd(out + i * KB_ + j, sred[0] + sred[1]);
}

extern "C" void kernel_launch(void* const* d_in, const int* in_sizes, int n_in,
                              void* d_out, int out_size, void* d_ws, size_t ws_size,
                              hipStream_t stream)
{
    const float* Q       = (const float*)d_in[0];
    const float* K       = (const float*)d_in[1];
    const float* alpha_p = (const float*)d_in[2];
    const int*   qmask   = (const int*)d_in[3];
    const int*   kmask   = (const int*)d_in[4];
    float*       out     = (float*)d_out;

    char* ws = (char*)d_ws;
    _Float16* Qt = (_Float16*)ws;
    _Float16* Kt = (_Float16*)(ws + (size_t)B_ * SEQ_ * HID_ * 2);

    hipMemsetAsync(d_out, 0, (size_t)out_size * sizeof(float), stream);

    prep_tile<<<QRB + KRB, 256, 0, stream>>>(Q, K, Qt, Kt);

    dim3 grid(SEQ_ / 128, KB_, B_);   // (st, j, i) = (4, 16, 8) = 512 blocks
    li_main<<<grid, 512, 0, stream>>>(Qt, Kt, alpha_p, kmask, qmask, out);
}

// Round 7
// 154.497 us; speedup vs baseline: 1.0556x; 1.0556x over previous
//
#include <hip/hip_runtime.h>
#include <stdint.h>

#define B_   8
#define KB_  16
#define SEQ_ 512
#define HID_ 768

#define NKB  (HID_ / 32)         // 24 k-blocks (32 halves each) per row
#define QRB  (B_  * SEQ_ / 16)   // 256 Q row-blocks of 16 rows
#define KRB  (KB_ * SEQ_ / 16)   // 512 K row-blocks

typedef __attribute__((ext_vector_type(4))) _Float16 half4;
typedef __attribute__((ext_vector_type(8))) _Float16 half8;
typedef __attribute__((ext_vector_type(4))) float    floatx4;

#define GLOBAL_AS __attribute__((address_space(1)))
#define LDS_AS    __attribute__((address_space(3)))

// async 16B/lane global->LDS copy: LDS dest = base + lane*16 (wave-uniform base)
static __device__ __forceinline__ void async_tile16(const _Float16* g, _Float16* l)
{
    __builtin_amdgcn_global_load_lds((const GLOBAL_AS uint32_t*)g,
                                     (LDS_AS uint32_t*)l, 16, 0, 0);
}

// ---------------- prepass: L2-normalize rows -> fp16 in MFMA-fragment-tiled layout ----
// Tile = 16 rows x 32 k = 1KB, lane-major: element(row,k) at lane = row | ((k>>3)<<4),
// idx = k&7. One 256-thread block per 16-row block.
#define LP 776   // LDS row stride in halves

__global__ __launch_bounds__(256)
void prep_tile(const float* __restrict__ Q, const float* __restrict__ K,
               _Float16* __restrict__ Qt, _Float16* __restrict__ Kt)
{
    const int rb = blockIdx.x;   // 0..767
    const float* src;
    _Float16*    dst;
    if (rb < QRB) { src = Q + (size_t)rb * 16 * HID_;          dst = Qt + (size_t)rb * NKB * 512; }
    else          { src = K + (size_t)(rb - QRB) * 16 * HID_;  dst = Kt + (size_t)(rb - QRB) * NKB * 512; }

    __shared__ _Float16 Ls[16 * LP];
    const int wave = threadIdx.x >> 6;
    const int lane = threadIdx.x & 63;

#pragma unroll
    for (int rr = 0; rr < 4; ++rr) {
        int row = wave * 4 + rr;
        const float* s = src + (size_t)row * HID_;
        float4 v[3];
        float ss = 0.f;
#pragma unroll
        for (int it = 0; it < 3; ++it) {
            v[it] = *(const float4*)(s + lane * 4 + it * 256);
            ss += v[it].x * v[it].x + v[it].y * v[it].y + v[it].z * v[it].z + v[it].w * v[it].w;
        }
#pragma unroll
        for (int m = 1; m < 64; m <<= 1) ss += __shfl_xor(ss, m, 64);
        float sc = 1.0f / fmaxf(sqrtf(ss), 1e-12f);
#pragma unroll
        for (int it = 0; it < 3; ++it) {
            half4 h = { (_Float16)(v[it].x * sc), (_Float16)(v[it].y * sc),
                        (_Float16)(v[it].z * sc), (_Float16)(v[it].w * sc) };
            *(half4*)(Ls + row * LP + lane * 4 + it * 256) = h;
        }
    }
    __syncthreads();

#pragma unroll
    for (int rep = 0; rep < 6; ++rep) {
        int slot = rep * 256 + threadIdx.x;      // 0..1535 = 24 tiles x 64 lanes
        int kb   = slot >> 6;
        int ln   = slot & 63;
        int row  = ln & 15;
        int ko   = kb * 32 + (ln >> 4) * 8;
        half8 h = *(const half8*)(Ls + row * LP + ko);
        *(half8*)(dst + (size_t)kb * 512 + (size_t)ln * 8) = h;
    }
}

// ---------------- fused main: (i,j,st) per block; both t-halves sequentially ----------
// 512 threads = 8 waves in 2 (row) x 4 (col); wave tile 64x64 per 256-col pass.
// Full-row sum-softmax across the two passes -> n/l -> q_mask -> one atomicAdd.
__global__ __launch_bounds__(512, 4)
void li_main(const _Float16* __restrict__ Qt, const _Float16* __restrict__ Kt,
             const float* __restrict__ alpha_p, const int* __restrict__ kmask,
             const int* __restrict__ qmask, float* __restrict__ out)
{
    const int st = blockIdx.x;   // 0..3
    const int j  = blockIdx.y;
    const int i  = blockIdx.z;

    // double-buffered staging: 24 tiles (8 Q + 16 K) x 512 halves per buffer = 24 KB
    __shared__ __align__(16) _Float16 smem[2 * 24 * 512];   // 49152 B
    __shared__ float lsum[4][128], nsum[4][128];
    __shared__ float sred[2];

    const int tid  = threadIdx.x;
    const int lane = tid & 63;
    const int wave = tid >> 6;        // 0..7
    const int quad = lane >> 4;
    const int l16  = lane & 15;
    const int wr   = wave >> 2;       // row half (0/1): rows wr*64..+63
    const int wc   = wave & 3;        // col quarter (0..3) within the 256-col pass

    const float araw  = *alpha_p;
    const float alpha = araw >= 0.f ? araw : 0.01f * araw;   // leaky_relu

    const int qbase = i * 32 + st * 8;

    for (int tb = 0; tb < 2; ++tb) {
        const int kbase = j * 32 + tb * 16;

        // staging assignment: wave stages tiles wave*3 .. wave*3+2 (8 Q + 16 K = 24)
        const _Float16* gsrc[3];
        _Float16*       ldst0[3];
#pragma unroll
        for (int q = 0; q < 3; ++q) {
            int t   = wave * 3 + q;
            int rbg = (t < 8) ? (qbase + t) : (kbase + (t - 8));
            const _Float16* base = (t < 8) ? Qt : Kt;
            gsrc[q]  = base + (size_t)rbg * NKB * 512 + (size_t)lane * 8;
            ldst0[q] = &smem[t * 512];
        }

        floatx4 acc[4][4];
#pragma unroll
        for (int rt = 0; rt < 4; ++rt)
#pragma unroll
            for (int ct = 0; ct < 4; ++ct)
                acc[rt][ct] = (floatx4){0.f, 0.f, 0.f, 0.f};

        // stage kb=0 into buffer 0 (pass-0 last reads were buf1: no WAR hazard; the
        // k-loop's first __syncthreads orders these DMA writes for all waves)
#pragma unroll
        for (int q = 0; q < 3; ++q)
            async_tile16(gsrc[q], ldst0[q]);

        for (int kb = 0; kb < NKB; ++kb) {
            const int b = kb & 1;
            __syncthreads();   // drains this-kb staging; fences prior reads of buf b^1
            if (kb + 1 < NKB) {
#pragma unroll
                for (int q = 0; q < 3; ++q)
                    async_tile16(gsrc[q] + (size_t)(kb + 1) * 512, ldst0[q] + (b ^ 1) * 24 * 512);
            }
            const _Float16* Qs = &smem[b * 24 * 512];
            const _Float16* Ks = Qs + 8 * 512;
            half8 af[4], bf[4];
#pragma unroll
            for (int rt = 0; rt < 4; ++rt)
                af[rt] = *(const half8*)(Qs + (wr * 4 + rt) * 512 + lane * 8);
#pragma unroll
            for (int ct = 0; ct < 4; ++ct)
                bf[ct] = *(const half8*)(Ks + (wc * 4 + ct) * 512 + lane * 8);
#pragma unroll
            for (int rt = 0; rt < 4; ++rt)
#pragma unroll
                for (int ct = 0; ct < 4; ++ct)
                    acc[rt][ct] = __builtin_amdgcn_mfma_f32_16x16x32_f16(af[rt], bf[ct], acc[rt][ct], 0, 0, 0);
        }

        // ---- epilogue: sum-softmax partials (logits in [-e,e] -> no max shift) ----
        const int* km = kmask + j * SEQ_ + tb * 256;
        int kmv[4]; float tgf[4];
#pragma unroll
        for (int ct = 0; ct < 4; ++ct) {
            int t_loc = wc * 64 + ct * 16 + l16;
            kmv[ct] = km[t_loc];
            tgf[ct] = (float)(tb * 256 + t_loc);
        }
#pragma unroll
        for (int rt = 0; rt < 4; ++rt) {
#pragma unroll
            for (int r = 0; r < 4; ++r) {
                float sgf = (float)(st * 128 + wr * 64 + rt * 16 + quad * 4 + r);
                float ps = 0.f, ns = 0.f;
#pragma unroll
                for (int ct = 0; ct < 4; ++ct) {
                    float cv = acc[rt][ct][r];
                    float e  = kmv[ct] ? __expf(cv * __expf(-alpha * fabsf(sgf - tgf[ct]))) : 0.f;
                    ps += e;
                    ns += e * cv;
                }
#pragma unroll
                for (int msk = 1; msk < 16; msk <<= 1) {
                    ps += __shfl_xor(ps, msk, 64);
                    ns += __shfl_xor(ns, msk, 64);
                }
                if (l16 == 0) {   // same lanes own (wc,rloc) in both passes: no race
                    int rloc = wr * 64 + rt * 16 + quad * 4 + r;
                    if (tb == 0) { lsum[wc][rloc]  = ps; nsum[wc][rloc]  = ns; }
                    else         { lsum[wc][rloc] += ps; nsum[wc][rloc] += ns; }
                }
            }
        }
    }
    __syncthreads();

    // merge 4 col-quarters -> per-row score; block-sum 128 rows -> one atomicAdd
    float sum = 0.f;
    if (tid < 128) {
        float l = lsum[0][tid] + lsum[1][tid] + lsum[2][tid] + lsum[3][tid];
        float n = nsum[0][tid] + nsum[1][tid] + nsum[2][tid] + nsum[3][tid];
        float sc = (l > 0.f) ? n / l : 0.f;
        if (qmask[i * SEQ_ + st * 128 + tid] == 0) sc = 0.f;
        sum = sc;
#pragma unroll
        for (int m = 1; m < 64; m <<= 1) sum += __shfl_xor(sum, m, 64);
        if (lane == 0) sred[wave] = sum;
    }
    __syncthreads();
    if (tid == 0) atomicAdd(out + i * KB_ + j, sred[0] + sred[1]);
}

extern "C" void kernel_launch(void* const* d_in, const int* in_sizes, int n_in,
                              void* d_out, int out_size, void* d_ws, size_t ws_size,
                              hipStream_t stream)
{
    const float* Q       = (const float*)d_in[0];
    const float* K       = (const float*)d_in[1];
    const float* alpha_p = (const float*)d_in[2];
    const int*   qmask   = (const int*)d_in[3];
    const int*   kmask   = (const int*)d_in[4];
    float*       out     = (float*)d_out;

    char* ws = (char*)d_ws;
    _Float16* Qt = (_Float16*)ws;
    _Float16* Kt = (_Float16*)(ws + (size_t)B_ * SEQ_ * HID_ * 2);

    hipMemsetAsync(d_out, 0, (size_t)out_size * sizeof(float), stream);

    prep_tile<<<QRB + KRB, 256, 0, stream>>>(Q, K, Qt, Kt);

    dim3 grid(SEQ_ / 128, KB_, B_);   // (st, j, i) = (4, 16, 8) = 512 blocks
    li_main<<<grid, 512, 0, stream>>>(Qt, Kt, alpha_p, kmask, qmask, out);
}

// Round 8
// 145.837 us; speedup vs baseline: 1.1182x; 1.0594x over previous
//
#include <hip/hip_runtime.h>
#include <stdint.h>

#define B_   8
#define KB_  16
#define SEQ_ 512
#define HID_ 768

#define NKB  (HID_ / 32)         // 24 k-blocks (32 halves each) per row
#define QRB  (B_  * SEQ_ / 16)   // 256 Q row-blocks of 16 rows
#define KRB  (KB_ * SEQ_ / 16)   // 512 K row-blocks

typedef __attribute__((ext_vector_type(4))) _Float16 half4;
typedef __attribute__((ext_vector_type(8))) _Float16 half8;
typedef __attribute__((ext_vector_type(4))) float    floatx4;

#define GLOBAL_AS __attribute__((address_space(1)))
#define LDS_AS    __attribute__((address_space(3)))

// async 16B/lane global->LDS copy: LDS dest = base + lane*16 (wave-uniform base)
static __device__ __forceinline__ void async_tile16(const _Float16* g, _Float16* l)
{
    __builtin_amdgcn_global_load_lds((const GLOBAL_AS uint32_t*)g,
                                     (LDS_AS uint32_t*)l, 16, 0, 0);
}

// ---------------- prepass: L2-normalize rows -> fp16 in MFMA-fragment-tiled layout ----
// Tile = 16 rows x 32 k = 1KB, lane-major: element(row,k) at lane = row | ((k>>3)<<4),
// idx = k&7. One 256-thread block per 16-row block.
#define LP 776   // LDS row stride in halves

__global__ __launch_bounds__(256)
void prep_tile(const float* __restrict__ Q, const float* __restrict__ K,
               _Float16* __restrict__ Qt, _Float16* __restrict__ Kt)
{
    const int rb = blockIdx.x;   // 0..767
    const float* src;
    _Float16*    dst;
    if (rb < QRB) { src = Q + (size_t)rb * 16 * HID_;          dst = Qt + (size_t)rb * NKB * 512; }
    else          { src = K + (size_t)(rb - QRB) * 16 * HID_;  dst = Kt + (size_t)(rb - QRB) * NKB * 512; }

    __shared__ _Float16 Ls[16 * LP];
    const int wave = threadIdx.x >> 6;
    const int lane = threadIdx.x & 63;

#pragma unroll
    for (int rr = 0; rr < 4; ++rr) {
        int row = wave * 4 + rr;
        const float* s = src + (size_t)row * HID_;
        float4 v[3];
        float ss = 0.f;
#pragma unroll
        for (int it = 0; it < 3; ++it) {
            v[it] = *(const float4*)(s + lane * 4 + it * 256);
            ss += v[it].x * v[it].x + v[it].y * v[it].y + v[it].z * v[it].z + v[it].w * v[it].w;
        }
#pragma unroll
        for (int m = 1; m < 64; m <<= 1) ss += __shfl_xor(ss, m, 64);
        float sc = 1.0f / fmaxf(sqrtf(ss), 1e-12f);
#pragma unroll
        for (int it = 0; it < 3; ++it) {
            half4 h = { (_Float16)(v[it].x * sc), (_Float16)(v[it].y * sc),
                        (_Float16)(v[it].z * sc), (_Float16)(v[it].w * sc) };
            *(half4*)(Ls + row * LP + lane * 4 + it * 256) = h;
        }
    }
    __syncthreads();

#pragma unroll
    for (int rep = 0; rep < 6; ++rep) {
        int slot = rep * 256 + threadIdx.x;      // 0..1535 = 24 tiles x 64 lanes
        int kb   = slot >> 6;
        int ln   = slot & 63;
        int row  = ln & 15;
        int ko   = kb * 32 + (ln >> 4) * 8;
        half8 h = *(const half8*)(Ls + row * LP + ko);
        *(half8*)(dst + (size_t)kb * 512 + (size_t)ln * 8) = h;
    }
}

// ---------------- phase 1: 128x128 tile per block, 4 waves, max co-residency ---------
// grid: x = st*4 + tb (16), y = j (16), z = i (8) -> 2048 blocks; 4 blocks/CU resident.
__global__ __launch_bounds__(256, 4)
void li_part(const _Float16* __restrict__ Qt, const _Float16* __restrict__ Kt,
             const float* __restrict__ alpha_p, const int* __restrict__ kmask,
             float* __restrict__ Pbuf)
{
    const int st = blockIdx.x >> 2;   // s tile (0..3), 128 rows
    const int tb = blockIdx.x & 3;    // t tile (0..3), 128 cols
    const int j  = blockIdx.y;
    const int i  = blockIdx.z;

    const int tid  = threadIdx.x;
    const int lane = tid & 63;
    const int wave = tid >> 6;        // 0..3
    const int quad = lane >> 4;
    const int l16  = lane & 15;
    const int wr   = wave >> 1;       // row half (0/1): rows wr*64..+63
    const int wc   = wave & 1;        // col half (0/1): cols wc*64..+63

    // double-buffered staging: 16 tiles (8 Q + 8 K) x 512 halves per buffer = 16 KB
    __shared__ __align__(16) _Float16 smem[2 * 16 * 512];   // 32768 B
    __shared__ float lred[2][128], nred[2][128];

    const float araw  = *alpha_p;
    const float alpha = araw >= 0.f ? araw : 0.01f * araw;   // leaky_relu

    const int qbase = i * 32 + st * 8;
    const int kbase = j * 32 + tb * 8;

    // staging assignment: wave stages tiles wave*4 .. wave*4+3 (8 Q then 8 K)
    const _Float16* gsrc[4];
    _Float16*       ldst0[4];
#pragma unroll
    for (int q = 0; q < 4; ++q) {
        int t   = wave * 4 + q;
        int rbg = (t < 8) ? (qbase + t) : (kbase + (t - 8));
        const _Float16* base = (t < 8) ? Qt : Kt;
        gsrc[q]  = base + (size_t)rbg * NKB * 512 + (size_t)lane * 8;
        ldst0[q] = &smem[t * 512];
    }

    floatx4 acc[4][4];
#pragma unroll
    for (int rt = 0; rt < 4; ++rt)
#pragma unroll
        for (int ct = 0; ct < 4; ++ct)
            acc[rt][ct] = (floatx4){0.f, 0.f, 0.f, 0.f};

    // stage kb=0 into buffer 0
#pragma unroll
    for (int q = 0; q < 4; ++q)
        async_tile16(gsrc[q], ldst0[q]);

    for (int kb = 0; kb < NKB; ++kb) {
        const int b = kb & 1;
        __syncthreads();   // drains this-kb staging; fences prior reads of buf b^1
        if (kb + 1 < NKB) {
#pragma unroll
            for (int q = 0; q < 4; ++q)
                async_tile16(gsrc[q] + (size_t)(kb + 1) * 512, ldst0[q] + (b ^ 1) * 16 * 512);
        }
        const _Float16* Qs = &smem[b * 16 * 512];
        const _Float16* Ks = Qs + 8 * 512;
        half8 af[4], bf[4];
#pragma unroll
        for (int rt = 0; rt < 4; ++rt)
            af[rt] = *(const half8*)(Qs + (wr * 4 + rt) * 512 + lane * 8);
#pragma unroll
        for (int ct = 0; ct < 4; ++ct)
            bf[ct] = *(const half8*)(Ks + (wc * 4 + ct) * 512 + lane * 8);
#pragma unroll
        for (int rt = 0; rt < 4; ++rt)
#pragma unroll
            for (int ct = 0; ct < 4; ++ct)
                acc[rt][ct] = __builtin_amdgcn_mfma_f32_16x16x32_f16(af[rt], bf[ct], acc[rt][ct], 0, 0, 0);
    }

    // ---- epilogue: sum-softmax partials (logits in [-e,e] -> no max shift) ----
    const int* km = kmask + j * SEQ_ + tb * 128;
    int kmv[4]; float tgf[4];
#pragma unroll
    for (int ct = 0; ct < 4; ++ct) {
        int t_loc = wc * 64 + ct * 16 + l16;
        kmv[ct] = km[t_loc];
        tgf[ct] = (float)(tb * 128 + t_loc);
    }
#pragma unroll
    for (int rt = 0; rt < 4; ++rt) {
#pragma unroll
        for (int r = 0; r < 4; ++r) {
            float sgf = (float)(st * 128 + wr * 64 + rt * 16 + quad * 4 + r);
            float ps = 0.f, ns = 0.f;
#pragma unroll
            for (int ct = 0; ct < 4; ++ct) {
                float cv = acc[rt][ct][r];
                float e  = kmv[ct] ? __expf(cv * __expf(-alpha * fabsf(sgf - tgf[ct]))) : 0.f;
                ps += e;
                ns += e * cv;
            }
#pragma unroll
            for (int msk = 1; msk < 16; msk <<= 1) {
                ps += __shfl_xor(ps, msk, 64);
                ns += __shfl_xor(ns, msk, 64);
            }
            if (l16 == 0) {
                int rloc = wr * 64 + rt * 16 + quad * 4 + r;
                lred[wc][rloc] = ps;
                nred[wc][rloc] = ns;
            }
        }
    }
    __syncthreads();

    // merge 2 col-halves; write one (l,n) partial per row for this t-tile
    if (tid < 128) {
        float l = lred[0][tid] + lred[1][tid];
        float n = nred[0][tid] + nred[1][tid];
        size_t base = (((size_t)(i * KB_ + j) * SEQ_) + st * 128 + tid) * 8 + tb * 2;
        Pbuf[base]     = l;
        Pbuf[base + 1] = n;
    }
}

// ---------------- phase 2: sum t-tile partials, apply q_mask, reduce over s ----------
__global__ __launch_bounds__(256)
void li_reduce(const float* __restrict__ Pbuf, const int* __restrict__ qmask,
               float* __restrict__ out)
{
    const int ij = blockIdx.x;
    const int i  = ij >> 4;           // KB_ == 16
    const int tid = threadIdx.x;
    __shared__ float red[4];

    float sum = 0.f;
#pragma unroll
    for (int rep = 0; rep < 2; ++rep) {
        int s = tid + rep * 256;
        const float4* p = (const float4*)(Pbuf + ((size_t)ij * SEQ_ + s) * 8);
        float4 a = p[0], b = p[1];
        float l = a.x + a.z + b.x + b.z;
        float n = a.y + a.w + b.y + b.w;
        float sc = (l > 0.f) ? n / l : 0.f;
        if (qmask[i * SEQ_ + s] == 0) sc = 0.f;
        sum += sc;
    }
#pragma unroll
    for (int m = 1; m < 64; m <<= 1) sum += __shfl_xor(sum, m, 64);
    if ((tid & 63) == 0) red[tid >> 6] = sum;
    __syncthreads();
    if (tid == 0) out[ij] = red[0] + red[1] + red[2] + red[3];
}

extern "C" void kernel_launch(void* const* d_in, const int* in_sizes, int n_in,
                              void* d_out, int out_size, void* d_ws, size_t ws_size,
                              hipStream_t stream)
{
    const float* Q       = (const float*)d_in[0];
    const float* K       = (const float*)d_in[1];
    const float* alpha_p = (const float*)d_in[2];
    const int*   qmask   = (const int*)d_in[3];
    const int*   kmask   = (const int*)d_in[4];
    float*       out     = (float*)d_out;

    char* ws = (char*)d_ws;
    _Float16* Qt   = (_Float16*)ws;
    _Float16* Kt   = (_Float16*)(ws + (size_t)B_ * SEQ_ * HID_ * 2);
    float*    Pbuf = (float*)   (ws + (size_t)(B_ + KB_) * SEQ_ * HID_ * 2);

    prep_tile<<<QRB + KRB, 256, 0, stream>>>(Q, K, Qt, Kt);

    dim3 grid(16, KB_, B_);   // (st*4+tb, j, i) = 2048 blocks
    li_part<<<grid, 256, 0, stream>>>(Qt, Kt, alpha_p, kmask, Pbuf);

    li_reduce<<<B_ * KB_, 256, 0, stream>>>(Pbuf, qmask, out);
}